// Round 28
// baseline (131.738 us; speedup 1.0000x reference)
//
#include <hip/hip_runtime.h>
#include <math.h>

#define N_NODES 50000
#define IN_CH   128
#define HEADS   4
#define HID     64
#define NEDGE   800000
#define EPS     1e-6f
#define LN_EPS  1e-5f
#define PAD     48                   // padded CSR row stride
#define MTILES  (N_NODES / 16)       // 3125 16-node M-tiles
#define NG      12500                // node u32-groups (4 packed u8 counters)

typedef __attribute__((ext_vector_type(8))) _Float16 f16x8;
typedef __attribute__((ext_vector_type(4))) float    f32x4;

// ---- cross-lane reduce helpers --------------------------------------
#define DPP_ADD_F(p, ctrl) \
    p += __int_as_float(__builtin_amdgcn_update_dpp(0, __float_as_int(p), ctrl, 0xF, 0xF, true))
#define REDUCE16_DPP(p) { DPP_ADD_F(p,0xB1); DPP_ADD_F(p,0x4E); \
                          DPP_ADD_F(p,0x141); DPP_ADD_F(p,0x140); }
#define REDUCE4_DPP(p)  { DPP_ADD_F(p,0xB1); DPP_ADD_F(p,0x4E); }
#define REDUCE64(p) { REDUCE16_DPP(p); p += __shfl_xor(p,16); p += __shfl_xor(p,32); }

// ---- shared MFMA GEMM body (one 16-node M-tile per wave) ------------
__device__ __forceinline__ void gemm_mtile(int mt, const float* __restrict__ x,
                                           const float* __restrict__ lin_w,
                                           float* __restrict__ h,
                                           float* __restrict__ inv_hn, int lane) {
    int node0 = mt * 16;
    int mrow  = lane & 15;
    int kg    = lane >> 4;
    const float4* xp = (const float4*)x;
    const float4* w4 = (const float4*)lin_w;

    f16x8 A[4];
#pragma unroll
    for (int s = 0; s < 4; ++s) {
        float4 u0 = xp[(node0 + mrow) * 32 + s * 8 + kg * 2];
        float4 u1 = xp[(node0 + mrow) * 32 + s * 8 + kg * 2 + 1];
        f16x8 a;
        a[0] = (_Float16)u0.x; a[1] = (_Float16)u0.y;
        a[2] = (_Float16)u0.z; a[3] = (_Float16)u0.w;
        a[4] = (_Float16)u1.x; a[5] = (_Float16)u1.y;
        a[6] = (_Float16)u1.z; a[7] = (_Float16)u1.w;
        A[s] = a;
    }
#pragma unroll
    for (int nt = 0; nt < 4; ++nt) {
        f32x4 C = {0.f, 0.f, 0.f, 0.f};
#pragma unroll
        for (int s = 0; s < 4; ++s) {
            int wrow = nt * 16 + mrow;
            float4 u0 = w4[wrow * 32 + s * 8 + kg * 2];
            float4 u1 = w4[wrow * 32 + s * 8 + kg * 2 + 1];
            f16x8 b;
            b[0] = (_Float16)u0.x; b[1] = (_Float16)u0.y;
            b[2] = (_Float16)u0.z; b[3] = (_Float16)u0.w;
            b[4] = (_Float16)u1.x; b[5] = (_Float16)u1.y;
            b[6] = (_Float16)u1.z; b[7] = (_Float16)u1.w;
            C = __builtin_amdgcn_mfma_f32_16x16x32_f16(A[s], b, C, 0, 0, 0);
        }
        float ss0 = C[0] * C[0], ss1 = C[1] * C[1];
        float ss2 = C[2] * C[2], ss3 = C[3] * C[3];
#pragma unroll
        for (int rr = 0; rr < 4; ++rr)
            h[(node0 + 4 * kg + rr) * HID + nt * 16 + mrow] = C[rr];
        REDUCE16_DPP(ss0); REDUCE16_DPP(ss1);
        REDUCE16_DPP(ss2); REDUCE16_DPP(ss3);
        if (mrow == 0) {
            inv_hn[(node0 + 4 * kg + 0) * HEADS + nt] = 1.0f / fmaxf(sqrtf(ss0), 1e-12f);
            inv_hn[(node0 + 4 * kg + 1) * HEADS + nt] = 1.0f / fmaxf(sqrtf(ss1), 1e-12f);
            inv_hn[(node0 + 4 * kg + 2) * HEADS + nt] = 1.0f / fmaxf(sqrtf(ss2), 1e-12f);
            inv_hn[(node0 + 4 * kg + 3) * HEADS + nt] = 1.0f / fmaxf(sqrtf(ss3), 1e-12f);
        }
    }
}

// ---------------- kernel A: segment histogram (+ optional GEMM) ------
// LDS-atomic histogram; atomic return = local rank. FUSE_GEMM: the
// MFMA GEMM co-schedules with the LDS-atomic phase (different pipes),
// TPB/64 waves x tiles-per-wave covers all M-tiles across the grid.
template<int SEGSN, int SEGN, bool FUSE_GEMM>
__global__ __launch_bounds__(512) void cnt_kernel(const int* __restrict__ ei,
                                                  unsigned* __restrict__ cnt,
                                                  unsigned char* __restrict__ lrank,
                                                  const float* __restrict__ x,
                                                  const float* __restrict__ lin_w,
                                                  float* __restrict__ h,
                                                  float* __restrict__ inv_hn) {
    __shared__ unsigned lc[NG];                  // 50KB
    for (int i = threadIdx.x; i < NG; i += 512) lc[i] = 0u;
    __syncthreads();
    int base = blockIdx.x * SEGN;
#pragma unroll 1
    for (int it = 0; it < SEGN / 512 + 1; ++it) {
        int el = it * 512 + threadIdx.x;
        if (el < SEGN) {
            int e = base + el;
            int n = ei[e];
            unsigned sh  = 8u * (n & 3);
            unsigned old = atomicAdd(&lc[n >> 2], 1u << sh);
            lrank[e] = (unsigned char)((old >> sh) & 0xFFu);
        }
    }

    if (FUSE_GEMM) {                             // overlap: MFMA + VMEM pipes
        int wave = threadIdx.x >> 6;
        int lane = threadIdx.x & 63;
        const int TPW = (MTILES + SEGSN * 8 - 1) / (SEGSN * 8); // tiles/wave
#pragma unroll
        for (int j = 0; j < TPW; ++j) {
            int mt = blockIdx.x * (8 * TPW) + j * 8 + wave;
            if (mt < MTILES) gemm_mtile(mt, x, lin_w, h, inv_hn, lane);
        }
    }

    __syncthreads();
    for (int i = threadIdx.x; i < NG; i += 512)
        cnt[blockIdx.x * NG + i] = lc[i];
}

// ---------------- kernel B: per-node prefix over segments + deg ------
template<int SEGSN>
__global__ __launch_bounds__(256) void prefix_kernel(unsigned* __restrict__ cnt,
                                                     unsigned* __restrict__ deg4) {
    int g = blockIdx.x * 256 + threadIdx.x;
    if (g >= NG) return;
    unsigned run = 0u;
#pragma unroll 1
    for (int s = 0; s < SEGSN; s += 4) {
        unsigned c0 = cnt[(s + 0) * NG + g];
        unsigned c1 = cnt[(s + 1) * NG + g];
        unsigned c2 = cnt[(s + 2) * NG + g];
        unsigned c3 = cnt[(s + 3) * NG + g];
        cnt[(s + 0) * NG + g] = run; run += c0;
        cnt[(s + 1) * NG + g] = run; run += c1;
        cnt[(s + 2) * NG + g] = run; run += c2;
        cnt[(s + 3) * NG + g] = run; run += c3;
    }
    deg4[g] = run;
}

// ---------------- kernel C: atomic-free CSR fill (pure, or + GEMM) ---
template<int SEGN, bool WITH_GEMM>
__global__ __launch_bounds__(256, 4) void fill_kernel(const int* __restrict__ ei,
                                                      const unsigned* __restrict__ sbase,
                                                      const unsigned char* __restrict__ lrank,
                                                      int* __restrict__ csr_col,
                                                      const float* __restrict__ x,
                                                      const float* __restrict__ lin_w,
                                                      float* __restrict__ h,
                                                      float* __restrict__ inv_hn) {
    int t = blockIdx.x * 256 + threadIdx.x;
    bool have_e = (t < NEDGE / 4);
    int4 r, c; unsigned lr4 = 0;
    int sb0 = 0, sb1 = 0, sb2 = 0, sb3 = 0;
    if (have_e) {
        r   = ((const int4*)ei)[t];
        c   = ((const int4*)(ei + NEDGE))[t];
        lr4 = ((const unsigned*)lrank)[t];
        int s = t / (SEGN / 4);
        sb0 = (sbase[s * NG + (r.x >> 2)] >> (8 * (r.x & 3))) & 0xFF;
        sb1 = (sbase[s * NG + (r.y >> 2)] >> (8 * (r.y & 3))) & 0xFF;
        sb2 = (sbase[s * NG + (r.z >> 2)] >> (8 * (r.z & 3))) & 0xFF;
        sb3 = (sbase[s * NG + (r.w >> 2)] >> (8 * (r.w & 3))) & 0xFF;
    }

    if (WITH_GEMM) {
        int mt = blockIdx.x * 4 + (threadIdx.x >> 6);
        if (mt < MTILES) gemm_mtile(mt, x, lin_w, h, inv_hn, threadIdx.x & 63);
    }

    if (have_e) {
        int sl0 = sb0 + ((lr4 >> 0)  & 0xFF);
        int sl1 = sb1 + ((lr4 >> 8)  & 0xFF);
        int sl2 = sb2 + ((lr4 >> 16) & 0xFF);
        int sl3 = sb3 + ((lr4 >> 24) & 0xFF);
        if (sl0 < PAD) __builtin_nontemporal_store(c.x, &csr_col[r.x * PAD + sl0]);
        if (sl1 < PAD) __builtin_nontemporal_store(c.y, &csr_col[r.y * PAD + sl1]);
        if (sl2 < PAD) __builtin_nontemporal_store(c.z, &csr_col[r.z * PAD + sl2]);
        if (sl3 < PAD) __builtin_nontemporal_store(c.w, &csr_col[r.w * PAD + sl3]);
    }
}

// ---------------- kernel E: gather (float4 pack, 4 edges/instr) ------
__global__ __launch_bounds__(256, 4) void gather_final(const unsigned char* __restrict__ deg8,
                                                       const int* __restrict__ csr_col,
                                                       const float* __restrict__ h,
                                                       const float* __restrict__ inv_hn,
                                                       const float* __restrict__ bcos_w,
                                                       const float* __restrict__ gamma,
                                                       const float* __restrict__ beta,
                                                       float* __restrict__ y) {
    __shared__ float4 wt4[16][65];
    __shared__ float rowbuf[4][HID];
    __shared__ float ivw[HID], gm[HID], bt[HID];

    for (int i = threadIdx.x; i < HID * (HID / 4); i += 256) {
        int j = i >> 4, k4 = i & 15;
        wt4[k4][j] = ((const float4*)bcos_w)[i];
    }
    if (threadIdx.x < HID) {
        gm[threadIdx.x] = gamma[threadIdx.x];
        bt[threadIdx.x] = beta[threadIdx.x];
    }
    __syncthreads();
    if (threadIdx.x < HID) {
        float ss = 0.f;
#pragma unroll
        for (int k4 = 0; k4 < 16; ++k4) {
            float4 q = wt4[k4][threadIdx.x];
            ss += q.x * q.x + q.y * q.y + q.z * q.z + q.w * q.w;
        }
        ivw[threadIdx.x] = 1.0f / fmaxf(sqrtf(ss), 1e-12f);
    }
    __syncthreads();

    int grp    = threadIdx.x >> 6;
    int lane   = threadIdx.x & 63;
    int e_slot = lane >> 4;
    int ch4    = lane & 15;
    int hd     = ch4 >> 2;

    const float4* h4 = (const float4*)h;

    for (int g = blockIdx.x; g < N_NODES / 4; g += gridDim.x) {
        int node = g * 4 + grp;
        float4 hq  = h4[node * 16 + ch4];
        float  ihr = inv_hn[node * HEADS + hd];
        float4 hrs4 = make_float4(hq.x * ihr, hq.y * ihr, hq.z * ihr, hq.w * ihr);
        int dg    = __builtin_amdgcn_readfirstlane(min((int)deg8[node], PAD));
        int start = node * PAD;

        float4 acc = make_float4(0.f, 0.f, 0.f, 0.f);
#pragma unroll 1
        for (int bb = 0; bb < dg; bb += 16) {
            int   cc[4];
            float4 hh[4];
            float ii[4];
#pragma unroll
            for (int s = 0; s < 4; ++s) {
                int e = bb + s * 4 + e_slot;
                int ix = (e < dg) ? e : dg - 1;
                cc[s] = csr_col[start + ix];
            }
#pragma unroll
            for (int s = 0; s < 4; ++s) hh[s] = h4[cc[s] * 16 + ch4];
#pragma unroll
            for (int s = 0; s < 4; ++s) ii[s] = inv_hn[cc[s] * HEADS + hd];
#pragma unroll
            for (int s = 0; s < 4; ++s) {
                float p = hh[s].x * hrs4.x + hh[s].y * hrs4.y
                        + hh[s].z * hrs4.z + hh[s].w * hrs4.w;
                REDUCE4_DPP(p);
                float sc = fminf(fmaxf(p * ii[s], EPS), 1.0f);  // B_EXP=2
                int e = bb + s * 4 + e_slot;
                sc = (e < dg) ? sc : 0.0f;
                acc.x = fmaf(hh[s].x, sc, acc.x);
                acc.y = fmaf(hh[s].y, sc, acc.y);
                acc.z = fmaf(hh[s].z, sc, acc.z);
                acc.w = fmaf(hh[s].w, sc, acc.w);
            }
        }
        acc.x += __shfl_xor(acc.x, 16); acc.x += __shfl_xor(acc.x, 32);
        acc.y += __shfl_xor(acc.y, 16); acc.y += __shfl_xor(acc.y, 32);
        acc.z += __shfl_xor(acc.z, 16); acc.z += __shfl_xor(acc.z, 32);
        acc.w += __shfl_xor(acc.w, 16); acc.w += __shfl_xor(acc.w, 32);

        if (lane < 16) ((float4*)rowbuf[grp])[ch4] = acc;
        float o = rowbuf[grp][lane];

        float ss = o * o;
        REDUCE64(ss);
        float inv_no = 1.0f / fmaxf(sqrtf(ss), 1e-12f);

        const float4* rb4 = (const float4*)rowbuf[grp];
        float lin = 0.f;
#pragma unroll
        for (int k4 = 0; k4 < 16; ++k4) {
            float4 a  = rb4[k4];
            float4 wv = wt4[k4][lane];
            lin += a.x * wv.x + a.y * wv.y + a.z * wv.z + a.w * wv.w;
        }

        float c2v = lin * inv_no * ivw[lane];
        c2v = fminf(fmaxf(c2v, EPS), 1.0f);
        float ob = lin * c2v;

        float mu = ob;
        REDUCE64(mu);
        mu *= (1.0f / 64.0f);
        float d = ob - mu;
        float var = d * d;
        REDUCE64(var);
        var *= (1.0f / 64.0f);
        float r = rsqrtf(var + LN_EPS);
        y[node * HID + lane] = d * r * gm[lane] + bt[lane];
    }
}

// ---------------------------------------------------------------------
extern "C" void kernel_launch(void* const* d_in, const int* in_sizes, int n_in,
                              void* d_out, int out_size, void* d_ws, size_t ws_size,
                              hipStream_t stream) {
    const float* x      = (const float*)d_in[0];
    const int*   ei     = (const int*)d_in[1];
    const float* lin_w  = (const float*)d_in[2];
    const float* bcos_w = (const float*)d_in[3];
    const float* gamma  = (const float*)d_in[4];
    const float* beta   = (const float*)d_in[5];
    float*       y      = (float*)d_out;

    const size_t LRANK_B = NEDGE;                      // 0.8MB
    const size_t H_B     = (size_t)N_NODES * HID * 4;  // 12.8MB
    const size_t INV_B   = (size_t)N_NODES * HEADS * 4;// 0.8MB
    const size_t DEG_B   = NG * 4;                     // 50KB
    const size_t CSR_B   = (size_t)N_NODES * PAD * 4;  // 9.6MB
    const size_t CNT200  = (size_t)200 * NG * 4;       // 10MB
    const size_t CNT100  = (size_t)100 * NG * 4;       // 5MB

    if (ws_size >= CNT200 + LRANK_B + H_B + INV_B + DEG_B + CSR_B) {
        // ---- SEGS=200 path: GEMM fused into cnt; fill is pure scatter ----
        char* p = (char*)d_ws;
        unsigned* cnt        = (unsigned*)p;            p += CNT200;
        unsigned char* lrank = (unsigned char*)p;       p += LRANK_B;
        float* h             = (float*)p;               p += H_B;
        float* inv_hn        = (float*)p;               p += INV_B;
        unsigned* deg4       = (unsigned*)p;            p += DEG_B;
        int* csr_col         = (int*)p;

        cnt_kernel<200, 4000, true><<<200, 512, 0, stream>>>(ei, cnt, lrank,
                                                             x, lin_w, h, inv_hn);
        prefix_kernel<200><<<(NG + 255) / 256, 256, 0, stream>>>(cnt, deg4);
        fill_kernel<4000, false><<<(NEDGE / 4 + 255) / 256, 256, 0, stream>>>(
            ei, cnt, lrank, csr_col, x, lin_w, h, inv_hn);
        gather_final<<<2048, 256, 0, stream>>>((const unsigned char*)deg4, csr_col,
                                               h, inv_hn, bcos_w, gamma, beta, y);
    } else {
        // ---- R27-proven fallback: SEGS=100, GEMM fused into fill ----
        char* p = (char*)d_ws;
        unsigned* cnt        = (unsigned*)p;            p += CNT100;
        unsigned char* lrank = (unsigned char*)p;       p += LRANK_B;
        float* h             = (float*)p;               p += H_B;
        float* inv_hn        = (float*)p;               p += INV_B;
        unsigned* deg4       = (unsigned*)p;            p += DEG_B;
        int* csr_col         = (int*)p;

        cnt_kernel<100, 8000, false><<<100, 512, 0, stream>>>(ei, cnt, lrank,
                                                              x, lin_w, h, inv_hn);
        prefix_kernel<100><<<(NG + 255) / 256, 256, 0, stream>>>(cnt, deg4);
        fill_kernel<8000, true><<<(MTILES + 3) / 4, 256, 0, stream>>>(
            ei, cnt, lrank, csr_col, x, lin_w, h, inv_hn);
        gather_final<<<2048, 256, 0, stream>>>((const unsigned char*)deg4, csr_col,
                                               h, inv_hn, bcos_w, gamma, beta, y);
    }
}

// Round 29
// 124.876 us; speedup vs baseline: 1.0550x; 1.0550x over previous
//
#include <hip/hip_runtime.h>
#include <math.h>

#define N_NODES 50000
#define IN_CH   128
#define HEADS   4
#define HID     64
#define NEDGE   800000
#define EPS     1e-6f
#define LN_EPS  1e-5f
#define PAD     48                   // padded CSR row stride
#define MTILES  (N_NODES / 16)       // 3125 16-node M-tiles
#define NG      12500                // node u32-groups (4 packed u8 counters)

typedef __attribute__((ext_vector_type(8))) _Float16 f16x8;
typedef __attribute__((ext_vector_type(4))) float    f32x4;

// ---- cross-lane reduce helpers --------------------------------------
#define DPP_ADD_F(p, ctrl) \
    p += __int_as_float(__builtin_amdgcn_update_dpp(0, __float_as_int(p), ctrl, 0xF, 0xF, true))
#define REDUCE16_DPP(p) { DPP_ADD_F(p,0xB1); DPP_ADD_F(p,0x4E); \
                          DPP_ADD_F(p,0x141); DPP_ADD_F(p,0x140); }
#define REDUCE4_DPP(p)  { DPP_ADD_F(p,0xB1); DPP_ADD_F(p,0x4E); }
#define REDUCE64(p) { REDUCE16_DPP(p); p += __shfl_xor(p,16); p += __shfl_xor(p,32); }

// ---- shared MFMA GEMM body (one 16-node M-tile per wave) ------------
__device__ __forceinline__ void gemm_mtile(int mt, const float* __restrict__ x,
                                           const float* __restrict__ lin_w,
                                           float* __restrict__ h,
                                           float* __restrict__ inv_hn, int lane) {
    int node0 = mt * 16;
    int mrow  = lane & 15;
    int kg    = lane >> 4;
    const float4* xp = (const float4*)x;
    const float4* w4 = (const float4*)lin_w;

    f16x8 A[4];
#pragma unroll
    for (int s = 0; s < 4; ++s) {
        float4 u0 = xp[(node0 + mrow) * 32 + s * 8 + kg * 2];
        float4 u1 = xp[(node0 + mrow) * 32 + s * 8 + kg * 2 + 1];
        f16x8 a;
        a[0] = (_Float16)u0.x; a[1] = (_Float16)u0.y;
        a[2] = (_Float16)u0.z; a[3] = (_Float16)u0.w;
        a[4] = (_Float16)u1.x; a[5] = (_Float16)u1.y;
        a[6] = (_Float16)u1.z; a[7] = (_Float16)u1.w;
        A[s] = a;
    }
#pragma unroll
    for (int nt = 0; nt < 4; ++nt) {
        f32x4 C = {0.f, 0.f, 0.f, 0.f};
#pragma unroll
        for (int s = 0; s < 4; ++s) {
            int wrow = nt * 16 + mrow;
            float4 u0 = w4[wrow * 32 + s * 8 + kg * 2];
            float4 u1 = w4[wrow * 32 + s * 8 + kg * 2 + 1];
            f16x8 b;
            b[0] = (_Float16)u0.x; b[1] = (_Float16)u0.y;
            b[2] = (_Float16)u0.z; b[3] = (_Float16)u0.w;
            b[4] = (_Float16)u1.x; b[5] = (_Float16)u1.y;
            b[6] = (_Float16)u1.z; b[7] = (_Float16)u1.w;
            C = __builtin_amdgcn_mfma_f32_16x16x32_f16(A[s], b, C, 0, 0, 0);
        }
        float ss0 = C[0] * C[0], ss1 = C[1] * C[1];
        float ss2 = C[2] * C[2], ss3 = C[3] * C[3];
#pragma unroll
        for (int rr = 0; rr < 4; ++rr)
            h[(node0 + 4 * kg + rr) * HID + nt * 16 + mrow] = C[rr];
        REDUCE16_DPP(ss0); REDUCE16_DPP(ss1);
        REDUCE16_DPP(ss2); REDUCE16_DPP(ss3);
        if (mrow == 0) {
            inv_hn[(node0 + 4 * kg + 0) * HEADS + nt] = 1.0f / fmaxf(sqrtf(ss0), 1e-12f);
            inv_hn[(node0 + 4 * kg + 1) * HEADS + nt] = 1.0f / fmaxf(sqrtf(ss1), 1e-12f);
            inv_hn[(node0 + 4 * kg + 2) * HEADS + nt] = 1.0f / fmaxf(sqrtf(ss2), 1e-12f);
            inv_hn[(node0 + 4 * kg + 3) * HEADS + nt] = 1.0f / fmaxf(sqrtf(ss3), 1e-12f);
        }
    }
}

// ---------------- kernel A: segment histogram (pure) -----------------
// LDS-atomic histogram; atomic return = local rank. No GEMM here
// (R28 lesson: 50KB LDS caps residency -> GEMM serializes, not hides).
template<int SEGN>
__global__ __launch_bounds__(512) void cnt_kernel(const int* __restrict__ ei,
                                                  unsigned* __restrict__ cnt,
                                                  unsigned char* __restrict__ lrank) {
    __shared__ unsigned lc[NG];                  // 50KB
    for (int i = threadIdx.x; i < NG; i += 512) lc[i] = 0u;
    __syncthreads();
    int base = blockIdx.x * SEGN;
#pragma unroll 1
    for (int it = 0; it < SEGN / 512 + 1; ++it) {
        int el = it * 512 + threadIdx.x;
        if (el < SEGN) {
            int e = base + el;
            int n = ei[e];
            unsigned sh  = 8u * (n & 3);
            unsigned old = atomicAdd(&lc[n >> 2], 1u << sh);
            lrank[e] = (unsigned char)((old >> sh) & 0xFFu);
        }
    }
    __syncthreads();
    for (int i = threadIdx.x; i < NG; i += 512)
        cnt[blockIdx.x * NG + i] = lc[i];
}

// ---------------- kernel B: per-node prefix over segments + deg ------
template<int SEGSN>
__global__ __launch_bounds__(256) void prefix_kernel(unsigned* __restrict__ cnt,
                                                     unsigned* __restrict__ deg4) {
    int g = blockIdx.x * 256 + threadIdx.x;
    if (g >= NG) return;
    unsigned run = 0u;
#pragma unroll 1
    for (int s = 0; s < SEGSN; s += 4) {
        unsigned c0 = cnt[(s + 0) * NG + g];
        unsigned c1 = cnt[(s + 1) * NG + g];
        unsigned c2 = cnt[(s + 2) * NG + g];
        unsigned c3 = cnt[(s + 3) * NG + g];
        cnt[(s + 0) * NG + g] = run; run += c0;
        cnt[(s + 1) * NG + g] = run; run += c1;
        cnt[(s + 2) * NG + g] = run; run += c2;
        cnt[(s + 3) * NG + g] = run; run += c3;
    }
    deg4[g] = run;
}

// ---------------- kernel C+D: atomic-free fill + fused MFMA GEMM -----
// R27-proven host for the GEMM: scatter loads issued early, GEMM in the
// middle (hides load+store latency), NT stores last.
template<int SEGN>
__global__ __launch_bounds__(256, 4) void fill_h_kernel(const float* __restrict__ x,
                                                        const float* __restrict__ lin_w,
                                                        float* __restrict__ h,
                                                        float* __restrict__ inv_hn,
                                                        const int* __restrict__ ei,
                                                        const unsigned* __restrict__ sbase,
                                                        const unsigned char* __restrict__ lrank,
                                                        int* __restrict__ csr_col) {
    int lane = threadIdx.x & 63;
    int wave = threadIdx.x >> 6;

    int t = blockIdx.x * 256 + threadIdx.x;
    bool have_e = (t < NEDGE / 4);
    int4 r, c; unsigned lr4 = 0;
    int sb0 = 0, sb1 = 0, sb2 = 0, sb3 = 0;
    if (have_e) {
        r   = ((const int4*)ei)[t];
        c   = ((const int4*)(ei + NEDGE))[t];
        lr4 = ((const unsigned*)lrank)[t];
        int s = t / (SEGN / 4);
        sb0 = (sbase[s * NG + (r.x >> 2)] >> (8 * (r.x & 3))) & 0xFF;
        sb1 = (sbase[s * NG + (r.y >> 2)] >> (8 * (r.y & 3))) & 0xFF;
        sb2 = (sbase[s * NG + (r.z >> 2)] >> (8 * (r.z & 3))) & 0xFF;
        sb3 = (sbase[s * NG + (r.w >> 2)] >> (8 * (r.w & 3))) & 0xFF;
    }

    int mt = blockIdx.x * 4 + wave;
    if (mt < MTILES) gemm_mtile(mt, x, lin_w, h, inv_hn, lane);

    if (have_e) {                         // loads long since landed
        int sl0 = sb0 + ((lr4 >> 0)  & 0xFF);
        int sl1 = sb1 + ((lr4 >> 8)  & 0xFF);
        int sl2 = sb2 + ((lr4 >> 16) & 0xFF);
        int sl3 = sb3 + ((lr4 >> 24) & 0xFF);
        if (sl0 < PAD) __builtin_nontemporal_store(c.x, &csr_col[r.x * PAD + sl0]);
        if (sl1 < PAD) __builtin_nontemporal_store(c.y, &csr_col[r.y * PAD + sl1]);
        if (sl2 < PAD) __builtin_nontemporal_store(c.z, &csr_col[r.z * PAD + sl2]);
        if (sl3 < PAD) __builtin_nontemporal_store(c.w, &csr_col[r.w * PAD + sl3]);
    }
}

// ---------------- kernel E: gather (float4 pack, 4 edges/instr) ------
__global__ __launch_bounds__(256, 4) void gather_final(const unsigned char* __restrict__ deg8,
                                                       const int* __restrict__ csr_col,
                                                       const float* __restrict__ h,
                                                       const float* __restrict__ inv_hn,
                                                       const float* __restrict__ bcos_w,
                                                       const float* __restrict__ gamma,
                                                       const float* __restrict__ beta,
                                                       float* __restrict__ y) {
    __shared__ float4 wt4[16][65];
    __shared__ float rowbuf[4][HID];
    __shared__ float ivw[HID], gm[HID], bt[HID];

    for (int i = threadIdx.x; i < HID * (HID / 4); i += 256) {
        int j = i >> 4, k4 = i & 15;
        wt4[k4][j] = ((const float4*)bcos_w)[i];
    }
    if (threadIdx.x < HID) {
        gm[threadIdx.x] = gamma[threadIdx.x];
        bt[threadIdx.x] = beta[threadIdx.x];
    }
    __syncthreads();
    if (threadIdx.x < HID) {
        float ss = 0.f;
#pragma unroll
        for (int k4 = 0; k4 < 16; ++k4) {
            float4 q = wt4[k4][threadIdx.x];
            ss += q.x * q.x + q.y * q.y + q.z * q.z + q.w * q.w;
        }
        ivw[threadIdx.x] = 1.0f / fmaxf(sqrtf(ss), 1e-12f);
    }
    __syncthreads();

    int grp    = threadIdx.x >> 6;
    int lane   = threadIdx.x & 63;
    int e_slot = lane >> 4;
    int ch4    = lane & 15;
    int hd     = ch4 >> 2;

    const float4* h4 = (const float4*)h;

    for (int g = blockIdx.x; g < N_NODES / 4; g += gridDim.x) {
        int node = g * 4 + grp;
        float4 hq  = h4[node * 16 + ch4];
        float  ihr = inv_hn[node * HEADS + hd];
        float4 hrs4 = make_float4(hq.x * ihr, hq.y * ihr, hq.z * ihr, hq.w * ihr);
        int dg    = __builtin_amdgcn_readfirstlane(min((int)deg8[node], PAD));
        int start = node * PAD;

        float4 acc = make_float4(0.f, 0.f, 0.f, 0.f);
#pragma unroll 1
        for (int bb = 0; bb < dg; bb += 16) {
            int   cc[4];
            float4 hh[4];
            float ii[4];
#pragma unroll
            for (int s = 0; s < 4; ++s) {
                int e = bb + s * 4 + e_slot;
                int ix = (e < dg) ? e : dg - 1;
                cc[s] = csr_col[start + ix];
            }
#pragma unroll
            for (int s = 0; s < 4; ++s) hh[s] = h4[cc[s] * 16 + ch4];
#pragma unroll
            for (int s = 0; s < 4; ++s) ii[s] = inv_hn[cc[s] * HEADS + hd];
#pragma unroll
            for (int s = 0; s < 4; ++s) {
                float p = hh[s].x * hrs4.x + hh[s].y * hrs4.y
                        + hh[s].z * hrs4.z + hh[s].w * hrs4.w;
                REDUCE4_DPP(p);
                float sc = fminf(fmaxf(p * ii[s], EPS), 1.0f);  // B_EXP=2
                int e = bb + s * 4 + e_slot;
                sc = (e < dg) ? sc : 0.0f;
                acc.x = fmaf(hh[s].x, sc, acc.x);
                acc.y = fmaf(hh[s].y, sc, acc.y);
                acc.z = fmaf(hh[s].z, sc, acc.z);
                acc.w = fmaf(hh[s].w, sc, acc.w);
            }
        }
        acc.x += __shfl_xor(acc.x, 16); acc.x += __shfl_xor(acc.x, 32);
        acc.y += __shfl_xor(acc.y, 16); acc.y += __shfl_xor(acc.y, 32);
        acc.z += __shfl_xor(acc.z, 16); acc.z += __shfl_xor(acc.z, 32);
        acc.w += __shfl_xor(acc.w, 16); acc.w += __shfl_xor(acc.w, 32);

        if (lane < 16) ((float4*)rowbuf[grp])[ch4] = acc;
        float o = rowbuf[grp][lane];

        float ss = o * o;
        REDUCE64(ss);
        float inv_no = 1.0f / fmaxf(sqrtf(ss), 1e-12f);

        const float4* rb4 = (const float4*)rowbuf[grp];
        float lin = 0.f;
#pragma unroll
        for (int k4 = 0; k4 < 16; ++k4) {
            float4 a  = rb4[k4];
            float4 wv = wt4[k4][lane];
            lin += a.x * wv.x + a.y * wv.y + a.z * wv.z + a.w * wv.w;
        }

        float c2v = lin * inv_no * ivw[lane];
        c2v = fminf(fmaxf(c2v, EPS), 1.0f);
        float ob = lin * c2v;

        float mu = ob;
        REDUCE64(mu);
        mu *= (1.0f / 64.0f);
        float d = ob - mu;
        float var = d * d;
        REDUCE64(var);
        var *= (1.0f / 64.0f);
        float r = rsqrtf(var + LN_EPS);
        y[node * HID + lane] = d * r * gm[lane] + bt[lane];
    }
}

// ---------------------------------------------------------------------
extern "C" void kernel_launch(void* const* d_in, const int* in_sizes, int n_in,
                              void* d_out, int out_size, void* d_ws, size_t ws_size,
                              hipStream_t stream) {
    const float* x      = (const float*)d_in[0];
    const int*   ei     = (const int*)d_in[1];
    const float* lin_w  = (const float*)d_in[2];
    const float* bcos_w = (const float*)d_in[3];
    const float* gamma  = (const float*)d_in[4];
    const float* beta   = (const float*)d_in[5];
    float*       y      = (float*)d_out;

    const size_t LRANK_B = NEDGE;                      // 0.8MB
    const size_t H_B     = (size_t)N_NODES * HID * 4;  // 12.8MB
    const size_t INV_B   = (size_t)N_NODES * HEADS * 4;// 0.8MB
    const size_t DEG_B   = NG * 4;                     // 50KB
    const size_t CSR_B   = (size_t)N_NODES * PAD * 4;  // 9.6MB
    const size_t CNT200  = (size_t)200 * NG * 4;       // 10MB
    const size_t CNT100  = (size_t)100 * NG * 4;       // 5MB

    if (ws_size >= CNT200 + LRANK_B + H_B + INV_B + DEG_B + CSR_B) {
        // ---- 200-segment build (2x cnt grid) + R27 fused fill+GEMM ----
        char* p = (char*)d_ws;
        unsigned* cnt        = (unsigned*)p;            p += CNT200;
        unsigned char* lrank = (unsigned char*)p;       p += LRANK_B;
        float* h             = (float*)p;               p += H_B;
        float* inv_hn        = (float*)p;               p += INV_B;
        unsigned* deg4       = (unsigned*)p;            p += DEG_B;
        int* csr_col         = (int*)p;

        cnt_kernel<4000><<<200, 512, 0, stream>>>(ei, cnt, lrank);
        prefix_kernel<200><<<(NG + 255) / 256, 256, 0, stream>>>(cnt, deg4);
        fill_h_kernel<4000><<<(MTILES + 3) / 4, 256, 0, stream>>>(
            x, lin_w, h, inv_hn, ei, cnt, lrank, csr_col);
        gather_final<<<2048, 256, 0, stream>>>((const unsigned char*)deg4, csr_col,
                                               h, inv_hn, bcos_w, gamma, beta, y);
    } else {
        // ---- R27-proven fallback: 100 segments ----
        char* p = (char*)d_ws;
        unsigned* cnt        = (unsigned*)p;            p += CNT100;
        unsigned char* lrank = (unsigned char*)p;       p += LRANK_B;
        float* h             = (float*)p;               p += H_B;
        float* inv_hn        = (float*)p;               p += INV_B;
        unsigned* deg4       = (unsigned*)p;            p += DEG_B;
        int* csr_col         = (int*)p;

        cnt_kernel<8000><<<100, 512, 0, stream>>>(ei, cnt, lrank);
        prefix_kernel<100><<<(NG + 255) / 256, 256, 0, stream>>>(cnt, deg4);
        fill_h_kernel<8000><<<(MTILES + 3) / 4, 256, 0, stream>>>(
            x, lin_w, h, inv_hn, ei, cnt, lrank, csr_col);
        gather_final<<<2048, 256, 0, stream>>>((const unsigned char*)deg4, csr_col,
                                               h, inv_hn, bcos_w, gamma, beta, y);
    }
}